// Round 1
// baseline (564.037 us; speedup 1.0000x reference)
//
#include <hip/hip_runtime.h>
#include <stdint.h>

#define NB 8
#define NN 1024

// ---------------- adjacency -> bitmask (self-loops fused) ----------------
// amask[b][i][w] bit j = (adj[b][i][w*64+j] > 0) || (w*64+j == i)
__global__ __launch_bounds__(256) void build_adjmask(const int* __restrict__ adj,
                                                     uint64_t* __restrict__ am) {
    int wave = blockIdx.x * 4 + (threadIdx.x >> 6);
    int lane = threadIdx.x & 63;
    int b = wave >> 10;
    int i = wave & 1023;
    const int* row = adj + ((size_t)b * NN + i) * NN;
    uint64_t* outp = am + ((size_t)b * NN + i) * 16;
    for (int it = 0; it < 16; ++it) {
        int j = it * 64 + lane;
        int v = (row[j] > 0) || (j == i);
        uint64_t m = __ballot(v);
        if (lane == 0) outp[it] = m;
    }
}

// ---------------- GEMM: O[m][n] = sum_k X[m][k] * W[n][k] ----------------
// 64x64 tile per block, 256 threads, 4x4 per thread, LDS staged transposed [k][row]
template<int K>
__global__ __launch_bounds__(256) void gemm_xwT(const float* __restrict__ X,
                                                const float* __restrict__ W,
                                                float* __restrict__ O, int ncol) {
    __shared__ float xs[64][68];   // [k][row]
    __shared__ float wsh[64][68];  // [k][col]
    int m0 = blockIdx.x * 64, n0 = blockIdx.y * 64;
    int tid = threadIdx.x;
    int tx = tid & 15, ty = tid >> 4;
    int r = tid >> 2, kb = (tid & 3) * 16;
    float acc[4][4] = {};
    for (int k0 = 0; k0 < K; k0 += 64) {
        const float4* xsrc = (const float4*)(X + (size_t)(m0 + r) * K + k0 + kb);
        const float4* wsrc = (const float4*)(W + (size_t)(n0 + r) * K + k0 + kb);
#pragma unroll
        for (int e = 0; e < 4; ++e) {
            float4 xv = xsrc[e], wv = wsrc[e];
            int k = kb + e * 4;
            xs[k+0][r] = xv.x; xs[k+1][r] = xv.y; xs[k+2][r] = xv.z; xs[k+3][r] = xv.w;
            wsh[k+0][r] = wv.x; wsh[k+1][r] = wv.y; wsh[k+2][r] = wv.z; wsh[k+3][r] = wv.w;
        }
        __syncthreads();
#pragma unroll 8
        for (int k = 0; k < 64; ++k) {
            float4 a  = *(const float4*)&xs[k][ty * 4];
            float4 bb = *(const float4*)&wsh[k][tx * 4];
            acc[0][0] += a.x*bb.x; acc[0][1] += a.x*bb.y; acc[0][2] += a.x*bb.z; acc[0][3] += a.x*bb.w;
            acc[1][0] += a.y*bb.x; acc[1][1] += a.y*bb.y; acc[1][2] += a.y*bb.z; acc[1][3] += a.y*bb.w;
            acc[2][0] += a.z*bb.x; acc[2][1] += a.z*bb.y; acc[2][2] += a.z*bb.z; acc[2][3] += a.z*bb.w;
            acc[3][0] += a.w*bb.x; acc[3][1] += a.w*bb.y; acc[3][2] += a.w*bb.z; acc[3][3] += a.w*bb.w;
        }
        __syncthreads();
    }
#pragma unroll
    for (int i2 = 0; i2 < 4; ++i2) {
        float4 o = make_float4(acc[i2][0], acc[i2][1], acc[i2][2], acc[i2][3]);
        *(float4*)(O + (size_t)(m0 + ty * 4 + i2) * ncol + n0 + tx * 4) = o;
    }
}

// ---------------- s/d scores: one wave per (b,n,hd) ----------------
// s_t,d_t stored transposed [B][nheads][N] for coalesced reads in aggregation
__global__ __launch_bounds__(256) void compute_sd(const float* __restrict__ Hf,
        const float* __restrict__ asrc, const float* __restrict__ adst,
        float* __restrict__ s_t, float* __restrict__ d_t, int nheads) {
    int wave = blockIdx.x * 4 + (threadIdx.x >> 6);
    int lane = threadIdx.x & 63;
    int hd = wave % nheads;
    int n = (wave / nheads) % NN;
    int b = wave / (nheads * NN);
    float hv = Hf[((size_t)b * NN + n) * (nheads * 64) + hd * 64 + lane];
    float sv = hv * asrc[hd * 64 + lane];
    float dv = hv * adst[hd * 64 + lane];
#pragma unroll
    for (int off = 32; off; off >>= 1) {
        sv += __shfl_down(sv, off);
        dv += __shfl_down(dv, off);
    }
    if (lane == 0) {
        s_t[((size_t)b * nheads + hd) * NN + n] = sv;
        d_t[((size_t)b * nheads + hd) * NN + n] = dv;
    }
}

// ---------------- fused masked-softmax aggregation ----------------
// block = (b, hd, 64-row i-tile); two-pass softmax; out = relu(P @ Hf + bias)
__global__ __launch_bounds__(256, 3) void gat_aggregate(
        const float* __restrict__ Hf, const uint64_t* __restrict__ am,
        const float* __restrict__ s_t, const float* __restrict__ d_t,
        const float* __restrict__ bias, float* __restrict__ Xout, int nheads) {
    __shared__ float s_lds[NN];        // 4 KB
    __shared__ float d_lds[64];
    __shared__ float m_lds[64];
    __shared__ float li_lds[64];
    __shared__ float red[64][4];
    __shared__ uint64_t adj_t[16][64]; // [word][i]  8 KB
    __shared__ float hs[64][68];       // [j][c]    17.4 KB
    __shared__ float wls[64][68];      // [j][i]    17.4 KB

    int i0 = blockIdx.x * 64;
    int hd = blockIdx.y;
    int b  = blockIdx.z;
    int HC = nheads * 64;
    int tid = threadIdx.x;

    const float* srow = s_t + ((size_t)b * nheads + hd) * NN;
    const float* drow = d_t + ((size_t)b * nheads + hd) * NN;
    for (int j = tid; j < NN; j += 256) s_lds[j] = srow[j];
    if (tid < 64) d_lds[tid] = drow[i0 + tid];
    for (int idx = tid; idx < 64 * 16; idx += 256) {
        int rr = idx >> 4, w = idx & 15;
        adj_t[w][rr] = am[((size_t)b * NN + i0 + rr) * 16 + w];
    }
    __syncthreads();

    // ---- pass 1: exact row max (m) and denom (l), 4 threads per row ----
    int il = tid >> 2, q = tid & 3;
    float d_i = d_lds[il];
    float mloc = -1e30f;
#pragma unroll
    for (int wb = 0; wb < 4; ++wb) {
        uint64_t word = adj_t[q * 4 + wb][il];
        int jbase = (q * 4 + wb) * 64;
        for (int jj = 0; jj < 64; ++jj) {
            if ((word >> jj) & 1ull) {
                float sc = s_lds[jbase + jj] + d_i;
                sc = sc > 0.f ? sc : 0.2f * sc;
                mloc = fmaxf(mloc, sc);
            }
        }
    }
    red[il][q] = mloc;
    __syncthreads();
    float m_i = fmaxf(fmaxf(red[il][0], red[il][1]), fmaxf(red[il][2], red[il][3]));
    float lloc = 0.f;
#pragma unroll
    for (int wb = 0; wb < 4; ++wb) {
        uint64_t word = adj_t[q * 4 + wb][il];
        int jbase = (q * 4 + wb) * 64;
        for (int jj = 0; jj < 64; ++jj) {
            if ((word >> jj) & 1ull) {
                float sc = s_lds[jbase + jj] + d_i;
                sc = sc > 0.f ? sc : 0.2f * sc;
                lloc += __expf(sc - m_i);
            }
        }
    }
    __syncthreads();
    red[il][q] = lloc;
    __syncthreads();
    if (q == 0) {
        m_lds[il] = m_i;
        li_lds[il] = 1.f / (red[il][0] + red[il][1] + red[il][2] + red[il][3]);
    }
    __syncthreads();

    // ---- pass 2: accumulate out[i][c] over 16 chunks of 64 j ----
    int tx = tid & 15, ty = tid >> 4;      // c-group / i-group for compute
    int lr = tid >> 2, lcb = (tid & 3) * 16;  // staging map for hs
    int wjj = tid >> 2, wib = (tid & 3) * 16; // staging map for wls
    float acc[4][4] = {};
    for (int jc = 0; jc < 16; ++jc) {
        int j0 = jc * 64;
        const float4* hsrc = (const float4*)(Hf + ((size_t)b * NN + j0 + lr) * HC + hd * 64 + lcb);
#pragma unroll
        for (int e = 0; e < 4; ++e) *(float4*)&hs[lr][lcb + e * 4] = hsrc[e];
        {
            float sj = s_lds[j0 + wjj];
#pragma unroll
            for (int g = 0; g < 4; ++g) {
                float4 w4;
                float* wp = (float*)&w4;
#pragma unroll
                for (int u = 0; u < 4; ++u) {
                    int i = wib + g * 4 + u;
                    float sc = sj + d_lds[i];
                    sc = sc > 0.f ? sc : 0.2f * sc;
                    float w = __expf(sc - m_lds[i]) * li_lds[i];
                    wp[u] = ((adj_t[jc][i] >> wjj) & 1ull) ? w : 0.f;
                }
                *(float4*)&wls[wjj][wib + g * 4] = w4;
            }
        }
        __syncthreads();
#pragma unroll 8
        for (int jj = 0; jj < 64; ++jj) {
            float4 wv = *(const float4*)&wls[jj][ty * 4];
            float4 hv = *(const float4*)&hs[jj][tx * 4];
            acc[0][0] += wv.x*hv.x; acc[0][1] += wv.x*hv.y; acc[0][2] += wv.x*hv.z; acc[0][3] += wv.x*hv.w;
            acc[1][0] += wv.y*hv.x; acc[1][1] += wv.y*hv.y; acc[1][2] += wv.y*hv.z; acc[1][3] += wv.y*hv.w;
            acc[2][0] += wv.z*hv.x; acc[2][1] += wv.z*hv.y; acc[2][2] += wv.z*hv.z; acc[2][3] += wv.z*hv.w;
            acc[3][0] += wv.w*hv.x; acc[3][1] += wv.w*hv.y; acc[3][2] += wv.w*hv.z; acc[3][3] += wv.w*hv.w;
        }
        __syncthreads();
    }
    const float* bptr = bias + hd * 64 + tx * 4;
    float b0 = bptr[0], b1v = bptr[1], b2v = bptr[2], b3v = bptr[3];
#pragma unroll
    for (int a = 0; a < 4; ++a) {
        float4 o;
        o.x = fmaxf(acc[a][0] + b0, 0.f);
        o.y = fmaxf(acc[a][1] + b1v, 0.f);
        o.z = fmaxf(acc[a][2] + b2v, 0.f);
        o.w = fmaxf(acc[a][3] + b3v, 0.f);
        *(float4*)(Xout + ((size_t)b * NN + i0 + ty * 4 + a) * HC + hd * 64 + tx * 4) = o;
    }
}

// ---------------- readout ----------------
__global__ __launch_bounds__(256) void colsum(const float* __restrict__ X3,
                                              float* __restrict__ gsum) {
    __shared__ float part[4][64];
    int b = blockIdx.x, tid = threadIdx.x;
    int c = tid & 63, r0 = tid >> 6;
    float s = 0.f;
    for (int n = r0; n < NN; n += 4) s += X3[((size_t)b * NN + n) * 64 + c];
    part[r0][c] = s;
    __syncthreads();
    if (tid < 64) gsum[b * 64 + tid] = part[0][tid] + part[1][tid] + part[2][tid] + part[3][tid];
}

__global__ __launch_bounds__(64) void gconst_k(const float* __restrict__ gsum,
        const float* __restrict__ wg, const float* __restrict__ bg,
        const float* __restrict__ wv, const float* __restrict__ bv,
        float* __restrict__ gc) {
    int b = blockIdx.x, o = threadIdx.x;
    float acc = bg[o];
    for (int c = 0; c < 64; ++c) acc += gsum[b * 64 + c] * wg[o * 64 + c];
    acc = fmaxf(acc, 0.f) * wv[64 + o];
#pragma unroll
    for (int off = 32; off; off >>= 1) acc += __shfl_down(acc, off);
    if (o == 0) gc[b] = acc + bv[0];
}

__global__ __launch_bounds__(256) void readout(const float* __restrict__ X3,
        const float* __restrict__ wn, const float* __restrict__ bn,
        const float* __restrict__ wv, const float* __restrict__ gc,
        float* __restrict__ outp) {
    __shared__ float wn_lds[64][65];
    __shared__ float xrow[4][64];
    int b = blockIdx.y, n0 = blockIdx.x * 64;
    int tid = threadIdx.x, w = tid >> 6, lane = tid & 63;
    for (int idx = tid; idx < 64 * 64; idx += 256) wn_lds[idx >> 6][idx & 63] = wn[idx];
    __syncthreads();
    float bno = bn[lane], wvo = wv[lane], gcb = gc[b];
    for (int it = 0; it < 16; ++it) {
        int n = n0 + w * 16 + it;
        xrow[w][lane] = X3[((size_t)b * NN + n) * 64 + lane];
        __syncthreads();
        float acc = bno;
#pragma unroll 8
        for (int c = 0; c < 64; ++c) acc += xrow[w][c] * wn_lds[lane][c];
        acc = fmaxf(acc, 0.f) * wvo;
#pragma unroll
        for (int off = 32; off; off >>= 1) acc += __shfl_down(acc, off);
        if (lane == 0) outp[(size_t)b * NN + n] = acc + gcb;
        __syncthreads();
    }
}

extern "C" void kernel_launch(void* const* d_in, const int* in_sizes, int n_in,
                              void* d_out, int out_size, void* d_ws, size_t ws_size,
                              hipStream_t stream) {
    const float* x0  = (const float*)d_in[0];
    const int*   adj = (const int*)  d_in[1];
    const float* w1  = (const float*)d_in[2];
    const float* as1 = (const float*)d_in[3];
    const float* ad1 = (const float*)d_in[4];
    const float* b1  = (const float*)d_in[5];
    const float* w2  = (const float*)d_in[6];
    const float* as2 = (const float*)d_in[7];
    const float* ad2 = (const float*)d_in[8];
    const float* b2  = (const float*)d_in[9];
    const float* w3  = (const float*)d_in[10];
    const float* as3 = (const float*)d_in[11];
    const float* ad3 = (const float*)d_in[12];
    const float* b3  = (const float*)d_in[13];
    const float* wn  = (const float*)d_in[14];
    const float* bn  = (const float*)d_in[15];
    const float* wg  = (const float*)d_in[16];
    const float* bg  = (const float*)d_in[17];
    const float* wv  = (const float*)d_in[18];
    const float* bv  = (const float*)d_in[19];
    float* outp = (float*)d_out;

    // workspace layout (~17.3 MB): amask 1MB | h_buf 8MB | x_buf 8MB | s,d 128KB ea | gsum | gconst
    char* wsb = (char*)d_ws;
    uint64_t* amask = (uint64_t*)wsb;
    float* h_buf = (float*)(wsb + (1u << 20));
    float* x_buf = (float*)(wsb + (9u << 20));
    float* s_buf = (float*)(wsb + (17u << 20));
    float* d_buf = (float*)(wsb + (17u << 20) + (1u << 17));
    float* gsum  = (float*)(wsb + (17u << 20) + (2u << 17));
    float* gcst  = (float*)(wsb + (17u << 20) + (2u << 17) + 4096);

    build_adjmask<<<2048, 256, 0, stream>>>(adj, amask);

    // layer 1 (Fin=64, H=4)
    gemm_xwT<64><<<dim3(128, 4), 256, 0, stream>>>(x0, w1, h_buf, 256);
    compute_sd<<<8192, 256, 0, stream>>>(h_buf, as1, ad1, s_buf, d_buf, 4);
    gat_aggregate<<<dim3(16, 4, 8), 256, 0, stream>>>(h_buf, amask, s_buf, d_buf, b1, x_buf, 4);

    // layer 2 (Fin=256, H=4)
    gemm_xwT<256><<<dim3(128, 4), 256, 0, stream>>>(x_buf, w2, h_buf, 256);
    compute_sd<<<8192, 256, 0, stream>>>(h_buf, as2, ad2, s_buf, d_buf, 4);
    gat_aggregate<<<dim3(16, 4, 8), 256, 0, stream>>>(h_buf, amask, s_buf, d_buf, b2, x_buf, 4);

    // layer 3 (Fin=256, H=1)
    gemm_xwT<256><<<dim3(128, 1), 256, 0, stream>>>(x_buf, w3, h_buf, 64);
    compute_sd<<<2048, 256, 0, stream>>>(h_buf, as3, ad3, s_buf, d_buf, 1);
    gat_aggregate<<<dim3(16, 1, 8), 256, 0, stream>>>(h_buf, amask, s_buf, d_buf, b3, x_buf, 1);

    // readout
    colsum<<<8, 256, 0, stream>>>(x_buf, gsum);
    gconst_k<<<8, 64, 0, stream>>>(gsum, wg, bg, wv, bv, gcst);
    readout<<<dim3(16, 8), 256, 0, stream>>>(x_buf, wn, bn, wv, gcst, outp);
}

// Round 2
// 323.137 us; speedup vs baseline: 1.7455x; 1.7455x over previous
//
#include <hip/hip_runtime.h>
#include <stdint.h>

#define NB 8
#define NN 1024

typedef short short8 __attribute__((ext_vector_type(8)));
typedef float floatx4 __attribute__((ext_vector_type(4)));

static __device__ __forceinline__ short f2bf(float x) {
    union { float f; uint32_t u; } v; v.f = x;
    uint32_t r = (v.u + 0x7fffu + ((v.u >> 16) & 1u)) >> 16;
    return (short)r;
}
static __device__ __forceinline__ float bf2f(ushort x) {
    union { uint32_t u; float f; } v; v.u = ((uint32_t)x) << 16;
    return v.f;
}

// ---------------- fp32 -> bf16 converter (n divisible by 1024) ----------------
__global__ __launch_bounds__(256) void cvt_bf16(const float* __restrict__ in,
                                                ushort* __restrict__ out, int n4) {
    int idx = blockIdx.x * 256 + threadIdx.x;
    if (idx >= n4) return;
    float4 v = ((const float4*)in)[idx];
    ushort4 o;
    o.x = (ushort)f2bf(v.x); o.y = (ushort)f2bf(v.y);
    o.z = (ushort)f2bf(v.z); o.w = (ushort)f2bf(v.w);
    ((ushort4*)out)[idx] = o;
}

// ---------------- adjacency -> bitmask (self-loops fused) ----------------
__global__ __launch_bounds__(256) void build_adjmask(const int* __restrict__ adj,
                                                     uint64_t* __restrict__ am) {
    int wave = blockIdx.x * 4 + (threadIdx.x >> 6);
    int lane = threadIdx.x & 63;
    int b = wave >> 10;
    int i = wave & 1023;
    const int* row = adj + ((size_t)b * NN + i) * NN;
    uint64_t* outp = am + ((size_t)b * NN + i) * 16;
    for (int it = 0; it < 16; ++it) {
        int j = it * 64 + lane;
        int v = (row[j] > 0) || (j == i);
        uint64_t m = __ballot(v);
        if (lane == 0) outp[it] = m;
    }
}

// ---------------- MFMA GEMM: out = X @ W^T, bf16 in, bf16 transposed out ----
// X bf16 [M][K] row-major, W bf16 [ncol][K] row-major.
// Output written TRANSPOSED per head: hbT[b][hd][c][node] bf16.
template<int K>
__global__ __launch_bounds__(256) void gemm_mfma(const ushort* __restrict__ X,
                                                 const ushort* __restrict__ Wt,
                                                 ushort* __restrict__ hbT, int nheads) {
    __shared__ ushort xs[64][72];
    __shared__ ushort ws[64][72];
    int m0 = blockIdx.x * 64, n0 = blockIdx.y * 64;
    int tid = threadIdx.x, w = tid >> 6, L = tid & 63;
    int m15 = L & 15, kq = L >> 4;
    floatx4 acc[4];
#pragma unroll
    for (int ct = 0; ct < 4; ++ct) acc[ct] = (floatx4){0.f, 0.f, 0.f, 0.f};

    for (int k0 = 0; k0 < K; k0 += 64) {
#pragma unroll
        for (int it = 0; it < 2; ++it) {
            int idx = tid + it * 256;          // 512 segs of 16B
            int r = idx >> 3, sg = idx & 7;
            *(uint4*)&xs[r][sg * 8] = *(const uint4*)&X[(size_t)(m0 + r) * K + k0 + sg * 8];
            *(uint4*)&ws[r][sg * 8] = *(const uint4*)&Wt[(size_t)(n0 + r) * K + k0 + sg * 8];
        }
        __syncthreads();
#pragma unroll
        for (int ks = 0; ks < 2; ++ks) {
            short8 a = *(const short8*)&xs[16 * w + m15][ks * 32 + kq * 8];
#pragma unroll
            for (int ct = 0; ct < 4; ++ct) {
                short8 bfr = *(const short8*)&ws[ct * 16 + m15][ks * 32 + kq * 8];
                acc[ct] = __builtin_amdgcn_mfma_f32_16x16x32_bf16(a, bfr, acc[ct], 0, 0, 0);
            }
        }
        __syncthreads();
    }
#pragma unroll
    for (int ct = 0; ct < 4; ++ct) {
        int ng = n0 + ct * 16 + m15;
        int hd = ng >> 6, c = ng & 63;
#pragma unroll
        for (int r = 0; r < 4; ++r) {
            int mg = m0 + 16 * w + kq * 4 + r;
            int bb = mg >> 10, node = mg & 1023;
            hbT[((size_t)(bb * nheads + hd) * 64 + c) * NN + node] = (ushort)f2bf(acc[ct][r]);
        }
    }
}

// ---------------- s/d scores from transposed bf16 H ----------------
// grid (NN/1024? -> (4, B*nheads)), block 256; thread handles one n via 4-stride? No:
// grid.x=4 chunks of 256 n; loop over c reads contiguous rows (coalesced).
__global__ __launch_bounds__(256) void compute_sd_T(const ushort* __restrict__ hbT,
        const float* __restrict__ asrc, const float* __restrict__ adst,
        float* __restrict__ s_t, float* __restrict__ d_t, int nheads) {
    int bh = blockIdx.y;
    int hd = bh % nheads;
    int n = blockIdx.x * 256 + threadIdx.x;
    const ushort* base = hbT + (size_t)bh * 64 * NN + n;
    float sv = 0.f, dv = 0.f;
#pragma unroll 8
    for (int c = 0; c < 64; ++c) {
        float h = bf2f(base[c * NN]);
        sv += h * asrc[hd * 64 + c];
        dv += h * adst[hd * 64 + c];
    }
    s_t[(size_t)bh * NN + n] = sv;
    d_t[(size_t)bh * NN + n] = dv;
}

// ---------------- MFMA masked-softmax aggregation ----------------
// block = (i-tile 64, hd, b), 4 waves; wave w computes rows [i0+16w, i0+16w+16) x 64 cols.
// Single pass: m_i = leaky(smax + d_i) upper bound; unnormalized P in A-frags
// (computed in registers), H B-frags from LDS-staged hbT chunk; divide by l at end.
__global__ __launch_bounds__(256) void gat_agg_mfma(
        const ushort* __restrict__ hbT, const uint64_t* __restrict__ am,
        const float* __restrict__ s_t, const float* __restrict__ d_t,
        const float* __restrict__ bias, float* __restrict__ Xout,
        ushort* __restrict__ Xb, int nheads, int write_f32) {
    __shared__ float s_lds[NN];          // 4 KB
    __shared__ float d_lds[64];
    __shared__ float li_lds[64];
    __shared__ float red4[4];
    __shared__ uint64_t adj_lds[16][64]; // [chunk][row] 8 KB
    __shared__ ushort hb_lds[64][72];    // [c][j] bf16 chunk, 16B-pad  9 KB

    int i0 = blockIdx.x * 64;
    int hd = blockIdx.y;
    int b  = blockIdx.z;
    int HC = nheads * 64;
    int tid = threadIdx.x, w = tid >> 6, L = tid & 63;
    int m15 = L & 15, kq = L >> 4;
    int irow = 16 * w + m15;             // row in tile served by this lane's A-frag

    // stage s (+ global max), d, adjacency
    const float* srow = s_t + ((size_t)b * nheads + hd) * NN;
    const float* drow = d_t + ((size_t)b * nheads + hd) * NN;
    float lm = -1e30f;
    for (int j = tid; j < NN; j += 256) {
        float v = srow[j];
        s_lds[j] = v;
        lm = fmaxf(lm, v);
    }
#pragma unroll
    for (int off = 32; off; off >>= 1) lm = fmaxf(lm, __shfl_xor(lm, off));
    if (L == 0) red4[w] = lm;
    if (tid < 64) d_lds[tid] = drow[i0 + tid];
#pragma unroll
    for (int it = 0; it < 4; ++it) {
        int idx = tid + it * 256;        // 1024 words
        int r = idx >> 4, wd = idx & 15;
        adj_lds[wd][r] = am[((size_t)b * NN + i0 + r) * 16 + wd];
    }
    __syncthreads();

    float smax = fmaxf(fmaxf(red4[0], red4[1]), fmaxf(red4[2], red4[3]));
    float d_i = d_lds[irow];
    float m_up = smax + d_i;
    m_up = m_up > 0.f ? m_up : 0.2f * m_up;   // exp-safe upper bound for this row

    floatx4 acc[4];
#pragma unroll
    for (int ct = 0; ct < 4; ++ct) acc[ct] = (floatx4){0.f, 0.f, 0.f, 0.f};
    float lsum = 0.f;

    const ushort* hbase = hbT + ((size_t)(b * nheads + hd) * 64) * NN;

    for (int jc = 0; jc < 16; ++jc) {
        // stage H chunk [64c][64j] bf16
#pragma unroll
        for (int it = 0; it < 2; ++it) {
            int idx = tid + it * 256;
            int c = idx >> 3, sg = idx & 7;
            *(uint4*)&hb_lds[c][sg * 8] = *(const uint4*)&hbase[(size_t)c * NN + jc * 64 + sg * 8];
        }
        __syncthreads();

        uint64_t word = adj_lds[jc][irow];
#pragma unroll
        for (int ks = 0; ks < 2; ++ks) {
            int jb = jc * 64 + ks * 32 + kq * 8;
            float sv[8];
            *(float4*)&sv[0] = *(const float4*)&s_lds[jb];
            *(float4*)&sv[4] = *(const float4*)&s_lds[jb + 4];
            unsigned byte = (unsigned)((word >> (ks * 32 + kq * 8)) & 0xffull);
            short8 afrag;
#pragma unroll
            for (int u = 0; u < 8; ++u) {
                float sc = sv[u] + d_i;
                sc = sc > 0.f ? sc : 0.2f * sc;
                float e = __expf(sc - m_up);
                e = ((byte >> u) & 1u) ? e : 0.f;
                lsum += e;
                ((short*)&afrag)[u] = f2bf(e);
            }
#pragma unroll
            for (int ct = 0; ct < 4; ++ct) {
                short8 bfr = *(const short8*)&hb_lds[ct * 16 + m15][ks * 32 + kq * 8];
                acc[ct] = __builtin_amdgcn_mfma_f32_16x16x32_bf16(afrag, bfr, acc[ct], 0, 0, 0);
            }
        }
        __syncthreads();
    }

    // reduce l across the 4 k-groups sharing a row, publish 1/l
    lsum += __shfl_xor(lsum, 16);
    lsum += __shfl_xor(lsum, 32);
    if (kq == 0) li_lds[16 * w + m15] = 1.f / lsum;
    __syncthreads();

    float bv4[4];
#pragma unroll
    for (int ct = 0; ct < 4; ++ct) bv4[ct] = bias[hd * 64 + ct * 16 + m15];
#pragma unroll
    for (int ct = 0; ct < 4; ++ct) {
#pragma unroll
        for (int r = 0; r < 4; ++r) {
            int row = 16 * w + kq * 4 + r;
            float v = acc[ct][r] * li_lds[row] + bv4[ct];
            v = fmaxf(v, 0.f);
            size_t off = ((size_t)(b * NN + i0 + row)) * HC + hd * 64 + ct * 16 + m15;
            Xb[off] = (ushort)f2bf(v);
            if (write_f32) Xout[off] = v;
        }
    }
}

// ---------------- readout ----------------
__global__ __launch_bounds__(256) void colsum(const float* __restrict__ X3,
                                              float* __restrict__ gsum) {
    __shared__ float part[4][64];
    int b = blockIdx.x, tid = threadIdx.x;
    int c = tid & 63, r0 = tid >> 6;
    float s = 0.f;
    for (int n = r0; n < NN; n += 4) s += X3[((size_t)b * NN + n) * 64 + c];
    part[r0][c] = s;
    __syncthreads();
    if (tid < 64) gsum[b * 64 + tid] = part[0][tid] + part[1][tid] + part[2][tid] + part[3][tid];
}

__global__ __launch_bounds__(64) void gconst_k(const float* __restrict__ gsum,
        const float* __restrict__ wg, const float* __restrict__ bg,
        const float* __restrict__ wv, const float* __restrict__ bv,
        float* __restrict__ gc) {
    int b = blockIdx.x, o = threadIdx.x;
    float acc = bg[o];
    for (int c = 0; c < 64; ++c) acc += gsum[b * 64 + c] * wg[o * 64 + c];
    acc = fmaxf(acc, 0.f) * wv[64 + o];
#pragma unroll
    for (int off = 32; off; off >>= 1) acc += __shfl_down(acc, off);
    if (o == 0) gc[b] = acc + bv[0];
}

__global__ __launch_bounds__(256) void readout(const float* __restrict__ X3,
        const float* __restrict__ wn, const float* __restrict__ bn,
        const float* __restrict__ wv, const float* __restrict__ gc,
        float* __restrict__ outp) {
    __shared__ float wn_lds[64][65];
    __shared__ float xrow[4][64];
    int b = blockIdx.y, n0 = blockIdx.x * 64;
    int tid = threadIdx.x, w = tid >> 6, lane = tid & 63;
    for (int idx = tid; idx < 64 * 64; idx += 256) wn_lds[idx >> 6][idx & 63] = wn[idx];
    __syncthreads();
    float bno = bn[lane], wvo = wv[lane], gcb = gc[b];
    for (int it = 0; it < 16; ++it) {
        int n = n0 + w * 16 + it;
        xrow[w][lane] = X3[((size_t)b * NN + n) * 64 + lane];
        __syncthreads();
        float acc = bno;
#pragma unroll 8
        for (int c = 0; c < 64; ++c) acc += xrow[w][c] * wn_lds[lane][c];
        acc = fmaxf(acc, 0.f) * wvo;
#pragma unroll
        for (int off = 32; off; off >>= 1) acc += __shfl_down(acc, off);
        if (lane == 0) outp[(size_t)b * NN + n] = acc + gcb;
        __syncthreads();
    }
}

extern "C" void kernel_launch(void* const* d_in, const int* in_sizes, int n_in,
                              void* d_out, int out_size, void* d_ws, size_t ws_size,
                              hipStream_t stream) {
    const float* x0  = (const float*)d_in[0];
    const int*   adj = (const int*)  d_in[1];
    const float* w1  = (const float*)d_in[2];
    const float* as1 = (const float*)d_in[3];
    const float* ad1 = (const float*)d_in[4];
    const float* b1  = (const float*)d_in[5];
    const float* w2  = (const float*)d_in[6];
    const float* as2 = (const float*)d_in[7];
    const float* ad2 = (const float*)d_in[8];
    const float* b2  = (const float*)d_in[9];
    const float* w3  = (const float*)d_in[10];
    const float* as3 = (const float*)d_in[11];
    const float* ad3 = (const float*)d_in[12];
    const float* b3  = (const float*)d_in[13];
    const float* wn  = (const float*)d_in[14];
    const float* bn  = (const float*)d_in[15];
    const float* wg  = (const float*)d_in[16];
    const float* bg  = (const float*)d_in[17];
    const float* wv  = (const float*)d_in[18];
    const float* bv  = (const float*)d_in[19];
    float* outp = (float*)d_out;

    // workspace layout (~16.5 MB, under round-1's 17.6 MB footprint)
    char* wsb = (char*)d_ws;
    uint64_t* amask = (uint64_t*)(wsb);                      // 1 MB
    ushort* hbT  = (ushort*)(wsb + (1u  << 20));             // 4 MB
    ushort* xbA  = (ushort*)(wsb + (5u  << 20));             // 4 MB
    ushort* xbB  = (ushort*)(wsb + (9u  << 20));             // 4 MB
    ushort* x0b  = (ushort*)(wsb + (13u << 20));             // 1 MB
    float*  x3   = (float*) (wsb + (14u << 20));             // 2 MB
    char* tail   = wsb + (16u << 20);
    float* s_buf = (float*)(tail);                           // 128 KB
    float* d_buf = (float*)(tail + (1u << 17));              // 128 KB
    ushort* wb1  = (ushort*)(tail + (2u << 17));             // 32 KB
    ushort* wb2  = (ushort*)(tail + (2u << 17) + (1u << 15));// 128 KB
    ushort* wb3  = (ushort*)(tail + (2u << 17) + (5u << 15));// 32 KB
    float* gsum  = (float*) (tail + (2u << 17) + (6u << 15));
    float* gcst  = (float*) (tail + (2u << 17) + (6u << 15) + 4096);

    // conversions + adjacency
    cvt_bf16<<<512, 256, 0, stream>>>(x0, x0b, 131072);      // 8192*64
    cvt_bf16<<<16,  256, 0, stream>>>(w1, wb1, 4096);        // 256*64
    cvt_bf16<<<64,  256, 0, stream>>>(w2, wb2, 16384);       // 256*256
    cvt_bf16<<<16,  256, 0, stream>>>(w3, wb3, 4096);        // 64*256
    build_adjmask<<<2048, 256, 0, stream>>>(adj, amask);

    // layer 1 (K=64, H=4)
    gemm_mfma<64><<<dim3(128, 4), 256, 0, stream>>>(x0b, wb1, hbT, 4);
    compute_sd_T<<<dim3(4, 32), 256, 0, stream>>>(hbT, as1, ad1, s_buf, d_buf, 4);
    gat_agg_mfma<<<dim3(16, 4, 8), 256, 0, stream>>>(hbT, amask, s_buf, d_buf, b1, x3, xbA, 4, 0);

    // layer 2 (K=256, H=4)
    gemm_mfma<256><<<dim3(128, 4), 256, 0, stream>>>(xbA, wb2, hbT, 4);
    compute_sd_T<<<dim3(4, 32), 256, 0, stream>>>(hbT, as2, ad2, s_buf, d_buf, 4);
    gat_agg_mfma<<<dim3(16, 4, 8), 256, 0, stream>>>(hbT, amask, s_buf, d_buf, b2, x3, xbB, 4, 0);

    // layer 3 (K=256, H=1)
    gemm_mfma<256><<<dim3(128, 1), 256, 0, stream>>>(xbB, wb3, hbT, 1);
    compute_sd_T<<<dim3(4, 8), 256, 0, stream>>>(hbT, as3, ad3, s_buf, d_buf, 1);
    gat_agg_mfma<<<dim3(16, 1, 8), 256, 0, stream>>>(hbT, amask, s_buf, d_buf, b3, x3, xbA, 1, 1);

    // readout
    colsum<<<8, 256, 0, stream>>>(x3, gsum);
    gconst_k<<<8, 64, 0, stream>>>(gsum, wg, bg, wv, bv, gcst);
    readout<<<dim3(16, 8), 256, 0, stream>>>(x3, wn, bn, wv, gcst, outp);
}

// Round 3
// 234.937 us; speedup vs baseline: 2.4008x; 1.3754x over previous
//
#include <hip/hip_runtime.h>
#include <stdint.h>

#define NB 8
#define NN 1024

typedef short short8 __attribute__((ext_vector_type(8)));
typedef float floatx4 __attribute__((ext_vector_type(4)));

static __device__ __forceinline__ short f2bf(float x) {
    union { float f; uint32_t u; } v; v.f = x;
    uint32_t r = (v.u + 0x7fffu + ((v.u >> 16) & 1u)) >> 16;
    return (short)r;
}

// ---------------- prep: fp32->bf16 conversions + gsum zero, one dispatch ----
// ranges (in float4 units): x0 131072 | w1 4096 | w2 16384 | w3 4096 | wn 1024 | gz 128
__global__ __launch_bounds__(256) void prep_cvt(
        const float* __restrict__ x0, const float* __restrict__ w1,
        const float* __restrict__ w2, const float* __restrict__ w3,
        const float* __restrict__ wn,
        ushort* __restrict__ x0b, ushort* __restrict__ wb1,
        ushort* __restrict__ wb2, ushort* __restrict__ wb3,
        ushort* __restrict__ wnb, float* __restrict__ gsum) {
    int idx = blockIdx.x * 256 + threadIdx.x;
    const float* src; ushort* dst; int li;
    if (idx < 131072)      { src = x0; dst = x0b; li = idx; }
    else if (idx < 135168) { src = w1; dst = wb1; li = idx - 131072; }
    else if (idx < 151552) { src = w2; dst = wb2; li = idx - 135168; }
    else if (idx < 155648) { src = w3; dst = wb3; li = idx - 151552; }
    else if (idx < 156672) { src = wn; dst = wnb; li = idx - 155648; }
    else if (idx < 156800) {
        ((float4*)gsum)[idx - 156672] = make_float4(0.f, 0.f, 0.f, 0.f);
        return;
    } else return;
    float4 v = ((const float4*)src)[li];
    ushort4 o;
    o.x = (ushort)f2bf(v.x); o.y = (ushort)f2bf(v.y);
    o.z = (ushort)f2bf(v.z); o.w = (ushort)f2bf(v.w);
    ((ushort4*)dst)[li] = o;
}

// ---------------- adjacency -> bitmask (self-loops fused) ----------------
__global__ __launch_bounds__(256) void build_adjmask(const int* __restrict__ adj,
                                                     uint64_t* __restrict__ am) {
    int wave = blockIdx.x * 4 + (threadIdx.x >> 6);
    int lane = threadIdx.x & 63;
    int b = wave >> 10;
    int i = wave & 1023;
    const int* row = adj + ((size_t)b * NN + i) * NN;
    uint64_t* outp = am + ((size_t)b * NN + i) * 16;
    for (int it = 0; it < 16; ++it) {
        int j = it * 64 + lane;
        int v = (row[j] > 0) || (j == i);
        uint64_t m = __ballot(v);
        if (lane == 0) outp[it] = m;
    }
}

// ---------------- MFMA GEMM: H = X @ W^T, with fused s/d score epilogue ----
// X bf16 [M=8192][K], Wt bf16 [ncol][K]. Block tile 64x64; blockIdx.y == head.
// Outputs: hbT[b][hd][c][node] bf16 (transposed), s_t/d_t[b*nheads+hd][node] f32.
template<int K>
__global__ __launch_bounds__(256) void gemm_mfma(const ushort* __restrict__ X,
        const ushort* __restrict__ Wt, ushort* __restrict__ hbT,
        const float* __restrict__ asrc, const float* __restrict__ adst,
        float* __restrict__ s_t, float* __restrict__ d_t, int nheads) {
    __shared__ ushort xs[64][72];
    __shared__ ushort ws[64][72];
    int m0 = blockIdx.x * 64, n0 = blockIdx.y * 64;
    int hd = blockIdx.y;                 // 64 cols per head segment
    int tid = threadIdx.x, w = tid >> 6, L = tid & 63;
    int m15 = L & 15, kq = L >> 4;
    floatx4 acc[4];
#pragma unroll
    for (int ct = 0; ct < 4; ++ct) acc[ct] = (floatx4){0.f, 0.f, 0.f, 0.f};

    for (int k0 = 0; k0 < K; k0 += 64) {
#pragma unroll
        for (int it = 0; it < 2; ++it) {
            int idx = tid + it * 256;
            int r = idx >> 3, sg = idx & 7;
            *(uint4*)&xs[r][sg * 8] = *(const uint4*)&X[(size_t)(m0 + r) * K + k0 + sg * 8];
            *(uint4*)&ws[r][sg * 8] = *(const uint4*)&Wt[(size_t)(n0 + r) * K + k0 + sg * 8];
        }
        __syncthreads();
#pragma unroll
        for (int ks = 0; ks < 2; ++ks) {
            short8 a = *(const short8*)&xs[16 * w + m15][ks * 32 + kq * 8];
#pragma unroll
            for (int ct = 0; ct < 4; ++ct) {
                short8 bfr = *(const short8*)&ws[ct * 16 + m15][ks * 32 + kq * 8];
                acc[ct] = __builtin_amdgcn_mfma_f32_16x16x32_bf16(a, bfr, acc[ct], 0, 0, 0);
            }
        }
        __syncthreads();
    }

    // ---- fused s/d epilogue: s[n]=h[n]·asrc, d[n]=h[n]·adst (per head) ----
    float asv[4], adv[4];
#pragma unroll
    for (int ct = 0; ct < 4; ++ct) {
        asv[ct] = asrc[hd * 64 + ct * 16 + m15];
        adv[ct] = adst[hd * 64 + ct * 16 + m15];
    }
#pragma unroll
    for (int r = 0; r < 4; ++r) {
        float sp = acc[0][r] * asv[0] + acc[1][r] * asv[1] + acc[2][r] * asv[2] + acc[3][r] * asv[3];
        float dp = acc[0][r] * adv[0] + acc[1][r] * adv[1] + acc[2][r] * adv[2] + acc[3][r] * adv[3];
#pragma unroll
        for (int off = 1; off < 16; off <<= 1) {
            sp += __shfl_xor(sp, off);
            dp += __shfl_xor(dp, off);
        }
        if (m15 == 0) {
            int mg = m0 + 16 * w + kq * 4 + r;
            int bb = mg >> 10, node = mg & 1023;
            s_t[((size_t)(bb * nheads + hd)) * NN + node] = sp;
            d_t[((size_t)(bb * nheads + hd)) * NN + node] = dp;
        }
    }

    // ---- write transposed bf16 H ----
#pragma unroll
    for (int ct = 0; ct < 4; ++ct) {
        int c = ct * 16 + m15;
#pragma unroll
        for (int r = 0; r < 4; ++r) {
            int mg = m0 + 16 * w + kq * 4 + r;
            int bb = mg >> 10, node = mg & 1023;
            hbT[((size_t)(bb * nheads + hd) * 64 + c) * NN + node] = (ushort)f2bf(acc[ct][r]);
        }
    }
}

// ---------------- MFMA masked-softmax aggregation ----------------
// Single pass: m_i = leaky(smax + d_i) upper bound; unnormalized P in A-frags,
// H B-frags from LDS-staged hbT chunk; divide by l in epilogue.
// do_colsum: also column-sum relu output into gsum[b][c] via atomicAdd (layer 3).
__global__ __launch_bounds__(256) void gat_agg_mfma(
        const ushort* __restrict__ hbT, const uint64_t* __restrict__ am,
        const float* __restrict__ s_t, const float* __restrict__ d_t,
        const float* __restrict__ bias, ushort* __restrict__ Xb,
        float* __restrict__ gsum, int nheads, int do_colsum) {
    __shared__ float s_lds[NN];          // 4 KB
    __shared__ float d_lds[64];
    __shared__ float li_lds[64];
    __shared__ float red4[4];
    __shared__ uint64_t adj_lds[16][64]; // 8 KB
    __shared__ ushort hb_lds[64][72];    // 9 KB

    int i0 = blockIdx.x * 64;
    int hd = blockIdx.y;
    int b  = blockIdx.z;
    int HC = nheads * 64;
    int tid = threadIdx.x, w = tid >> 6, L = tid & 63;
    int m15 = L & 15, kq = L >> 4;
    int irow = 16 * w + m15;

    const float* srow = s_t + ((size_t)b * nheads + hd) * NN;
    const float* drow = d_t + ((size_t)b * nheads + hd) * NN;
    float lm = -1e30f;
    for (int j = tid; j < NN; j += 256) {
        float v = srow[j];
        s_lds[j] = v;
        lm = fmaxf(lm, v);
    }
#pragma unroll
    for (int off = 32; off; off >>= 1) lm = fmaxf(lm, __shfl_xor(lm, off));
    if (L == 0) red4[w] = lm;
    if (tid < 64) d_lds[tid] = drow[i0 + tid];
#pragma unroll
    for (int it = 0; it < 4; ++it) {
        int idx = tid + it * 256;
        int r = idx >> 4, wd = idx & 15;
        adj_lds[wd][r] = am[((size_t)b * NN + i0 + r) * 16 + wd];
    }
    __syncthreads();

    float smax = fmaxf(fmaxf(red4[0], red4[1]), fmaxf(red4[2], red4[3]));
    float d_i = d_lds[irow];
    float m_up = smax + d_i;
    m_up = m_up > 0.f ? m_up : 0.2f * m_up;

    floatx4 acc[4];
#pragma unroll
    for (int ct = 0; ct < 4; ++ct) acc[ct] = (floatx4){0.f, 0.f, 0.f, 0.f};
    float lsum = 0.f;

    const ushort* hbase = hbT + ((size_t)(b * nheads + hd) * 64) * NN;

    for (int jc = 0; jc < 16; ++jc) {
#pragma unroll
        for (int it = 0; it < 2; ++it) {
            int idx = tid + it * 256;
            int c = idx >> 3, sg = idx & 7;
            *(uint4*)&hb_lds[c][sg * 8] = *(const uint4*)&hbase[(size_t)c * NN + jc * 64 + sg * 8];
        }
        __syncthreads();

        uint64_t word = adj_lds[jc][irow];
#pragma unroll
        for (int ks = 0; ks < 2; ++ks) {
            int jb = jc * 64 + ks * 32 + kq * 8;
            float sv[8];
            *(float4*)&sv[0] = *(const float4*)&s_lds[jb];
            *(float4*)&sv[4] = *(const float4*)&s_lds[jb + 4];
            unsigned byte = (unsigned)((word >> (ks * 32 + kq * 8)) & 0xffull);
            short8 afrag;
#pragma unroll
            for (int u = 0; u < 8; ++u) {
                float sc = sv[u] + d_i;
                sc = sc > 0.f ? sc : 0.2f * sc;
                float e = __expf(sc - m_up);
                e = ((byte >> u) & 1u) ? e : 0.f;
                lsum += e;
                ((short*)&afrag)[u] = f2bf(e);
            }
#pragma unroll
            for (int ct = 0; ct < 4; ++ct) {
                short8 bfr = *(const short8*)&hb_lds[ct * 16 + m15][ks * 32 + kq * 8];
                acc[ct] = __builtin_amdgcn_mfma_f32_16x16x32_bf16(afrag, bfr, acc[ct], 0, 0, 0);
            }
        }
        __syncthreads();
    }

    lsum += __shfl_xor(lsum, 16);
    lsum += __shfl_xor(lsum, 32);
    if (kq == 0) li_lds[16 * w + m15] = 1.f / lsum;
    __syncthreads();

    float bv4[4];
#pragma unroll
    for (int ct = 0; ct < 4; ++ct) bv4[ct] = bias[hd * 64 + ct * 16 + m15];
#pragma unroll
    for (int ct = 0; ct < 4; ++ct) {
        float cs = 0.f;
#pragma unroll
        for (int r = 0; r < 4; ++r) {
            int row = 16 * w + kq * 4 + r;
            float v = acc[ct][r] * li_lds[row] + bv4[ct];
            v = fmaxf(v, 0.f);
            cs += v;
            size_t off = ((size_t)(b * NN + i0 + row)) * HC + hd * 64 + ct * 16 + m15;
            Xb[off] = (ushort)f2bf(v);
        }
        if (do_colsum) {
            cs += __shfl_xor(cs, 16);
            cs += __shfl_xor(cs, 32);
            if (kq == 0) atomicAdd(&gsum[b * 64 + ct * 16 + m15], cs);
        }
    }
}

// ---------------- fused readout: gc + relu(X@wn.T+bn)·wv + gc ----------------
// grid (16, 8); block handles 64 nodes. gc[b] computed redundantly by wave 0.
__global__ __launch_bounds__(256) void readout_fused(
        const ushort* __restrict__ xb, const ushort* __restrict__ wnb,
        const float* __restrict__ bn, const float* __restrict__ wg,
        const float* __restrict__ bg, const float* __restrict__ wv,
        const float* __restrict__ bv, const float* __restrict__ gsum,
        float* __restrict__ outp) {
    __shared__ ushort xs[64][72];
    __shared__ ushort wns[64][72];
    __shared__ float gcs;
    int b = blockIdx.y, n0 = blockIdx.x * 64;
    int tid = threadIdx.x, w = tid >> 6, L = tid & 63;
    int m15 = L & 15, kq = L >> 4;
#pragma unroll
    for (int it = 0; it < 2; ++it) {
        int idx = tid + it * 256;
        int r = idx >> 3, sg = idx & 7;
        *(uint4*)&xs[r][sg * 8]  = *(const uint4*)&xb[(size_t)(b * NN + n0 + r) * 64 + sg * 8];
        *(uint4*)&wns[r][sg * 8] = *(const uint4*)&wnb[r * 64 + sg * 8];
    }
    if (tid < 64) {
        float acc = bg[tid];
#pragma unroll 8
        for (int c = 0; c < 64; ++c) acc += gsum[b * 64 + c] * wg[tid * 64 + c];
        acc = fmaxf(acc, 0.f) * wv[64 + tid];
#pragma unroll
        for (int off = 32; off; off >>= 1) acc += __shfl_down(acc, off);
        if (tid == 0) gcs = acc + bv[0];
    }
    __syncthreads();

    floatx4 acc[4];
#pragma unroll
    for (int ct = 0; ct < 4; ++ct) acc[ct] = (floatx4){0.f, 0.f, 0.f, 0.f};
#pragma unroll
    for (int ks = 0; ks < 2; ++ks) {
        short8 a = *(const short8*)&xs[16 * w + m15][ks * 32 + kq * 8];
#pragma unroll
        for (int ct = 0; ct < 4; ++ct) {
            short8 bfr = *(const short8*)&wns[ct * 16 + m15][ks * 32 + kq * 8];
            acc[ct] = __builtin_amdgcn_mfma_f32_16x16x32_bf16(a, bfr, acc[ct], 0, 0, 0);
        }
    }
    float bnv[4], wvv[4];
#pragma unroll
    for (int ct = 0; ct < 4; ++ct) {
        bnv[ct] = bn[ct * 16 + m15];
        wvv[ct] = wv[ct * 16 + m15];
    }
    float gc = gcs;
#pragma unroll
    for (int r = 0; r < 4; ++r) {
        float rp = 0.f;
#pragma unroll
        for (int ct = 0; ct < 4; ++ct)
            rp += fmaxf(acc[ct][r] + bnv[ct], 0.f) * wvv[ct];
#pragma unroll
        for (int off = 1; off < 16; off <<= 1) rp += __shfl_xor(rp, off);
        if (m15 == 0)
            outp[(size_t)b * NN + n0 + 16 * w + kq * 4 + r] = rp + gc;
    }
}

extern "C" void kernel_launch(void* const* d_in, const int* in_sizes, int n_in,
                              void* d_out, int out_size, void* d_ws, size_t ws_size,
                              hipStream_t stream) {
    const float* x0  = (const float*)d_in[0];
    const int*   adj = (const int*)  d_in[1];
    const float* w1  = (const float*)d_in[2];
    const float* as1 = (const float*)d_in[3];
    const float* ad1 = (const float*)d_in[4];
    const float* b1  = (const float*)d_in[5];
    const float* w2  = (const float*)d_in[6];
    const float* as2 = (const float*)d_in[7];
    const float* ad2 = (const float*)d_in[8];
    const float* b2  = (const float*)d_in[9];
    const float* w3  = (const float*)d_in[10];
    const float* as3 = (const float*)d_in[11];
    const float* ad3 = (const float*)d_in[12];
    const float* b3  = (const float*)d_in[13];
    const float* wn  = (const float*)d_in[14];
    const float* bn  = (const float*)d_in[15];
    const float* wg  = (const float*)d_in[16];
    const float* bg  = (const float*)d_in[17];
    const float* wv  = (const float*)d_in[18];
    const float* bv  = (const float*)d_in[19];
    float* outp = (float*)d_out;

    // workspace (~14.5 MB)
    char* wsb = (char*)d_ws;
    uint64_t* amask = (uint64_t*)(wsb);                      // 1 MB
    ushort* hbT  = (ushort*)(wsb + (1u  << 20));             // 4 MB
    ushort* xbA  = (ushort*)(wsb + (5u  << 20));             // 4 MB
    ushort* xbB  = (ushort*)(wsb + (9u  << 20));             // 4 MB
    ushort* x0b  = (ushort*)(wsb + (13u << 20));             // 1 MB
    char* tail   = wsb + (14u << 20);
    float* s_buf = (float*)(tail);                           // 128 KB
    float* d_buf = (float*)(tail + (1u << 17));              // 128 KB
    ushort* wb1  = (ushort*)(tail + (2u << 17));             // 32 KB
    ushort* wb2  = (ushort*)(tail + (2u << 17) + (1u << 15));// 128 KB
    ushort* wb3  = (ushort*)(tail + (2u << 17) + (5u << 15));// 32 KB
    ushort* wnb  = (ushort*)(tail + (2u << 17) + (6u << 15));// 8 KB
    float* gsum  = (float*) (tail + (2u << 17) + (6u << 15) + (1u << 13)); // 2 KB

    prep_cvt<<<613, 256, 0, stream>>>(x0, w1, w2, w3, wn, x0b, wb1, wb2, wb3, wnb, gsum);
    build_adjmask<<<2048, 256, 0, stream>>>(adj, amask);

    // layer 1 (K=64, H=4)
    gemm_mfma<64><<<dim3(128, 4), 256, 0, stream>>>(x0b, wb1, hbT, as1, ad1, s_buf, d_buf, 4);
    gat_agg_mfma<<<dim3(16, 4, 8), 256, 0, stream>>>(hbT, amask, s_buf, d_buf, b1, xbA, gsum, 4, 0);

    // layer 2 (K=256, H=4)
    gemm_mfma<256><<<dim3(128, 4), 256, 0, stream>>>(xbA, wb2, hbT, as2, ad2, s_buf, d_buf, 4);
    gat_agg_mfma<<<dim3(16, 4, 8), 256, 0, stream>>>(hbT, amask, s_buf, d_buf, b2, xbB, gsum, 4, 0);

    // layer 3 (K=256, H=1) + fused column-sum into gsum
    gemm_mfma<256><<<dim3(128, 1), 256, 0, stream>>>(xbB, wb3, hbT, as3, ad3, s_buf, d_buf, 1);
    gat_agg_mfma<<<dim3(16, 1, 8), 256, 0, stream>>>(hbT, amask, s_buf, d_buf, b3, xbA, gsum, 1, 1);

    // fused readout (gc + node transform + combine)
    readout_fused<<<dim3(16, 8), 256, 0, stream>>>(xbA, wnb, bn, wg, bg, wv, bv, gsum, outp);
}

// Round 4
// 208.446 us; speedup vs baseline: 2.7059x; 1.1271x over previous
//
#include <hip/hip_runtime.h>
#include <stdint.h>

#define NB 8
#define NN 1024
#define LOG2E 1.44269504088896f

typedef short short8 __attribute__((ext_vector_type(8)));
typedef float floatx4 __attribute__((ext_vector_type(4)));

static __device__ __forceinline__ short f2bf(float x) {   // round-nearest-even
    union { float f; uint32_t u; } v; v.f = x;
    uint32_t r = (v.u + 0x7fffu + ((v.u >> 16) & 1u)) >> 16;
    return (short)r;
}

// ---------------- prep: adjacency bitmask + fp32->bf16 cvt + gsum zero ------
__global__ __launch_bounds__(256) void prep_all(const int* __restrict__ adj,
        uint64_t* __restrict__ am,
        const float* __restrict__ x0, const float* __restrict__ w1,
        const float* __restrict__ w2, const float* __restrict__ w3,
        const float* __restrict__ wn,
        ushort* __restrict__ x0b, ushort* __restrict__ wb1,
        ushort* __restrict__ wb2, ushort* __restrict__ wb3,
        ushort* __restrict__ wnb, float* __restrict__ gsum) {
    if (blockIdx.x < 2048) {
        int wave = blockIdx.x * 4 + (threadIdx.x >> 6);
        int lane = threadIdx.x & 63;
        int b = wave >> 10;
        int i = wave & 1023;
        const int* row = adj + ((size_t)b * NN + i) * NN;
        uint64_t* outp = am + ((size_t)b * NN + i) * 16;
        for (int it = 0; it < 16; ++it) {
            int j = it * 64 + lane;
            int v = (row[j] > 0) || (j == i);
            uint64_t m = __ballot(v);
            if (lane == 0) outp[it] = m;
        }
        return;
    }
    int idx = (blockIdx.x - 2048) * 256 + threadIdx.x;
    const float* src; ushort* dst; int li;
    if (idx < 131072)      { src = x0; dst = x0b; li = idx; }
    else if (idx < 135168) { src = w1; dst = wb1; li = idx - 131072; }
    else if (idx < 151552) { src = w2; dst = wb2; li = idx - 135168; }
    else if (idx < 155648) { src = w3; dst = wb3; li = idx - 151552; }
    else if (idx < 156672) { src = wn; dst = wnb; li = idx - 155648; }
    else if (idx < 156800) {
        ((float4*)gsum)[idx - 156672] = make_float4(0.f, 0.f, 0.f, 0.f);
        return;
    } else return;
    float4 v = ((const float4*)src)[li];
    ushort4 o;
    o.x = (ushort)f2bf(v.x); o.y = (ushort)f2bf(v.y);
    o.z = (ushort)f2bf(v.z); o.w = (ushort)f2bf(v.w);
    ((ushort4*)dst)[li] = o;
}

// ---------------- MFMA GEMM: H = X @ W^T, fused s/d epilogue, LDS-transposed
// output hbT[b][hd][c][node] bf16. smem stride 88 (16B aligned, 2-way banks).
template<int K>
__global__ __launch_bounds__(256, 4) void gemm_mfma(const ushort* __restrict__ X,
        const ushort* __restrict__ Wt, ushort* __restrict__ hbT,
        const float* __restrict__ asrc, const float* __restrict__ adst,
        float* __restrict__ s_t, float* __restrict__ d_t, int nheads) {
    __shared__ ushort smem[2][64][88];   // [0]=X tile, [1]=W tile; 22.5 KB
    int m0 = blockIdx.x * 64, n0 = blockIdx.y * 64;
    int hd = blockIdx.y;
    int tid = threadIdx.x, w = tid >> 6, L = tid & 63;
    int m15 = L & 15, kq = L >> 4;
    floatx4 acc[4];
#pragma unroll
    for (int ct = 0; ct < 4; ++ct) acc[ct] = (floatx4){0.f, 0.f, 0.f, 0.f};

    for (int k0 = 0; k0 < K; k0 += 64) {
#pragma unroll
        for (int it = 0; it < 2; ++it) {
            int idx = tid + it * 256;
            int r = idx >> 3, sg = idx & 7;
            *(uint4*)&smem[0][r][sg * 8] = *(const uint4*)&X[(size_t)(m0 + r) * K + k0 + sg * 8];
            *(uint4*)&smem[1][r][sg * 8] = *(const uint4*)&Wt[(size_t)(n0 + r) * K + k0 + sg * 8];
        }
        __syncthreads();
#pragma unroll
        for (int ks = 0; ks < 2; ++ks) {
            short8 a = *(const short8*)&smem[0][16 * w + m15][ks * 32 + kq * 8];
#pragma unroll
            for (int ct = 0; ct < 4; ++ct) {
                short8 bfr = *(const short8*)&smem[1][ct * 16 + m15][ks * 32 + kq * 8];
                acc[ct] = __builtin_amdgcn_mfma_f32_16x16x32_bf16(a, bfr, acc[ct], 0, 0, 0);
            }
        }
        __syncthreads();
    }

    // ---- fused s/d epilogue (registers + shuffles only) ----
    float asv[4], adv[4];
#pragma unroll
    for (int ct = 0; ct < 4; ++ct) {
        asv[ct] = asrc[hd * 64 + ct * 16 + m15];
        adv[ct] = adst[hd * 64 + ct * 16 + m15];
    }
#pragma unroll
    for (int r = 0; r < 4; ++r) {
        float sp = acc[0][r] * asv[0] + acc[1][r] * asv[1] + acc[2][r] * asv[2] + acc[3][r] * asv[3];
        float dp = acc[0][r] * adv[0] + acc[1][r] * adv[1] + acc[2][r] * adv[2] + acc[3][r] * adv[3];
#pragma unroll
        for (int off = 1; off < 16; off <<= 1) {
            sp += __shfl_xor(sp, off);
            dp += __shfl_xor(dp, off);
        }
        if (m15 == 0) {
            int mg = m0 + 16 * w + kq * 4 + r;
            int bb = mg >> 10, node = mg & 1023;
            s_t[((size_t)(bb * nheads + hd)) * NN + node] = sp;
            d_t[((size_t)(bb * nheads + hd)) * NN + node] = dp;
        }
    }

    // ---- transpose through LDS, then coalesced 16B stores ----
    ushort* tb = (ushort*)smem;          // stride 80 (160 B, 16B aligned)
#pragma unroll
    for (int ct = 0; ct < 4; ++ct)
#pragma unroll
        for (int r = 0; r < 4; ++r)
            tb[(ct * 16 + m15) * 80 + 16 * w + kq * 4 + r] = (ushort)f2bf(acc[ct][r]);
    __syncthreads();
    int bb = m0 >> 10, node0 = m0 & 1023;
    size_t base = ((size_t)(bb * nheads + hd) * 64) * NN + node0;
    int c = tid >> 2, s2 = (tid & 3) * 2;
#pragma unroll
    for (int e = 0; e < 2; ++e) {
        int sg = s2 + e;
        *(uint4*)&hbT[base + (size_t)c * NN + sg * 8] = *(const uint4*)&tb[c * 80 + sg * 8];
    }
}

// ---------------- MFMA masked-softmax aggregation, j-split wave pairs -------
// grid (32, nheads, 8): 32-row i-tiles. Waves 0,1 (pair 0): rows 0-15/16-31,
// j in [0,512); waves 2,3 (pair 1): same rows, j in [512,1024). Partial accs
// and softmax denoms combined through LDS at the end.
__global__ __launch_bounds__(256, 4) void gat_agg_mfma(
        const ushort* __restrict__ hbT, const uint64_t* __restrict__ am,
        const float* __restrict__ s_t, const float* __restrict__ d_t,
        const float* __restrict__ bias, ushort* __restrict__ Xb,
        float* __restrict__ gsum, int nheads, int do_colsum) {
    __shared__ float s_lds[NN];            // 4 KB
    __shared__ float d_lds[32];
    __shared__ float li_lds[32];
    __shared__ float red4[4];
    __shared__ float lsum_part[32];
    __shared__ uint64_t adj_lds[16][32];   // 4 KB
    __shared__ ushort hb[2][64][88];       // 22.5 KB (one buffer per pair)

    int i0 = blockIdx.x * 32;
    int hd = blockIdx.y;
    int b  = blockIdx.z;
    int HC = nheads * 64;
    int tid = threadIdx.x, w = tid >> 6, L = tid & 63;
    int m15 = L & 15, kq = L >> 4;
    int p = w >> 1, q = w & 1;             // pair, row-half
    int tp = tid & 127;                    // thread-in-pair

    const float* srow = s_t + ((size_t)b * nheads + hd) * NN;
    const float* drow = d_t + ((size_t)b * nheads + hd) * NN;
    float lm = -1e30f;
    for (int j = tid; j < NN; j += 256) {
        float v = srow[j];
        s_lds[j] = v;
        lm = fmaxf(lm, v);
    }
#pragma unroll
    for (int off = 32; off; off >>= 1) lm = fmaxf(lm, __shfl_xor(lm, off));
    if (L == 0) red4[w] = lm;
    if (tid < 32) d_lds[tid] = drow[i0 + tid];
#pragma unroll
    for (int it = 0; it < 2; ++it) {
        int idx = tid + it * 256;          // 512 words
        int r = idx >> 4, wd = idx & 15;
        adj_lds[wd][r] = am[((size_t)b * NN + i0 + r) * 16 + wd];
    }
    __syncthreads();

    float smax = fmaxf(fmaxf(red4[0], red4[1]), fmaxf(red4[2], red4[3]));
    float d_i = d_lds[16 * q + m15];       // this lane's A-fragment row
    float m_up = smax + d_i;
    m_up = m_up > 0.f ? m_up : 0.2f * m_up;
    float m2n = -m_up * LOG2E;

    floatx4 acc[4];
#pragma unroll
    for (int ct = 0; ct < 4; ++ct) acc[ct] = (floatx4){0.f, 0.f, 0.f, 0.f};
    float lsum = 0.f;

    const ushort* hbase = hbT + ((size_t)(b * nheads + hd) * 64) * NN;

    for (int t = 0; t < 8; ++t) {
        int jc = p * 8 + t;
        // stage this pair's H chunk [64c][64j]
#pragma unroll
        for (int it = 0; it < 4; ++it) {
            int idx = tp + it * 128;       // 0..511 segs of 16B
            int c = idx >> 3, sg = idx & 7;
            *(uint4*)&hb[p][c][sg * 8] = *(const uint4*)&hbase[(size_t)c * NN + jc * 64 + sg * 8];
        }
        __syncthreads();

        uint64_t word = adj_lds[jc][16 * q + m15];
#pragma unroll
        for (int ks = 0; ks < 2; ++ks) {
            int jb = jc * 64 + ks * 32 + kq * 8;
            float sv[8];
            *(float4*)&sv[0] = *(const float4*)&s_lds[jb];
            *(float4*)&sv[4] = *(const float4*)&s_lds[jb + 4];
            unsigned byte = (unsigned)((word >> (ks * 32 + kq * 8)) & 0xffull);
            short8 afrag;
#pragma unroll
            for (int u = 0; u < 8; ++u) {
                float sc = sv[u] + d_i;
                float lk = fmaxf(sc, 0.2f * sc);
#if __has_builtin(__builtin_amdgcn_exp2f)
                float arg = __builtin_fmaf(lk, LOG2E, m2n);
                arg = ((byte >> u) & 1u) ? arg : -1e30f;
                float e = __builtin_amdgcn_exp2f(arg);
#else
                float e = __expf(lk - m_up);
                e = ((byte >> u) & 1u) ? e : 0.f;
#endif
                lsum += e;
                ((ushort*)&afrag)[u] = (ushort)(__float_as_uint(e) >> 16);
            }
#pragma unroll
            for (int ct = 0; ct < 4; ++ct) {
                short8 bfr = *(const short8*)&hb[p][ct * 16 + m15][ks * 32 + kq * 8];
                acc[ct] = __builtin_amdgcn_mfma_f32_16x16x32_bf16(afrag, bfr, acc[ct], 0, 0, 0);
            }
        }
        __syncthreads();
    }

    // row-total partial denom (sum over kq groups)
    lsum += __shfl_xor(lsum, 16);
    lsum += __shfl_xor(lsum, 32);

    // pair 1 publishes partial acc + denom; pair 0 combines
    float* accbuf = (float*)&hb[0][0][0];  // [32][66] f32 overlay (chunks done)
    if (p == 1) {
#pragma unroll
        for (int ct = 0; ct < 4; ++ct)
#pragma unroll
            for (int r = 0; r < 4; ++r)
                accbuf[(16 * q + kq * 4 + r) * 66 + ct * 16 + m15] = acc[ct][r];
        if (kq == 0) lsum_part[16 * q + m15] = lsum;
    }
    __syncthreads();
    if (p == 0) {
#pragma unroll
        for (int ct = 0; ct < 4; ++ct)
#pragma unroll
            for (int r = 0; r < 4; ++r)
                acc[ct][r] += accbuf[(16 * q + kq * 4 + r) * 66 + ct * 16 + m15];
        float ltot = lsum + lsum_part[16 * q + m15];
        if (kq == 0) li_lds[16 * q + m15] = 1.f / ltot;
    }
    __syncthreads();

    if (p == 0) {
        float bv4[4];
#pragma unroll
        for (int ct = 0; ct < 4; ++ct) bv4[ct] = bias[hd * 64 + ct * 16 + m15];
#pragma unroll
        for (int ct = 0; ct < 4; ++ct) {
            float cs = 0.f;
#pragma unroll
            for (int r = 0; r < 4; ++r) {
                int row = 16 * q + kq * 4 + r;
                float v = acc[ct][r] * li_lds[row] + bv4[ct];
                v = fmaxf(v, 0.f);
                cs += v;
                size_t off = ((size_t)(b * NN + i0 + row)) * HC + hd * 64 + ct * 16 + m15;
                Xb[off] = (ushort)f2bf(v);
            }
            if (do_colsum) {
                cs += __shfl_xor(cs, 16);
                cs += __shfl_xor(cs, 32);
                if (kq == 0) atomicAdd(&gsum[b * 64 + ct * 16 + m15], cs);
            }
        }
    }
}

// ---------------- fused readout: gc + relu(X@wn.T+bn)·wv + gc ----------------
__global__ __launch_bounds__(256) void readout_fused(
        const ushort* __restrict__ xb, const ushort* __restrict__ wnb,
        const float* __restrict__ bn, const float* __restrict__ wg,
        const float* __restrict__ bg, const float* __restrict__ wv,
        const float* __restrict__ bv, const float* __restrict__ gsum,
        float* __restrict__ outp) {
    __shared__ ushort xs[64][88];
    __shared__ ushort wns[64][88];
    __shared__ float gcs;
    int b = blockIdx.y, n0 = blockIdx.x * 64;
    int tid = threadIdx.x, w = tid >> 6, L = tid & 63;
    int m15 = L & 15, kq = L >> 4;
#pragma unroll
    for (int it = 0; it < 2; ++it) {
        int idx = tid + it * 256;
        int r = idx >> 3, sg = idx & 7;
        *(uint4*)&xs[r][sg * 8]  = *(const uint4*)&xb[(size_t)(b * NN + n0 + r) * 64 + sg * 8];
        *(uint4*)&wns[r][sg * 8] = *(const uint4*)&wnb[r * 64 + sg * 8];
    }
    if (tid < 64) {
        float acc = bg[tid];
#pragma unroll 8
        for (int c = 0; c < 64; ++c) acc += gsum[b * 64 + c] * wg[tid * 64 + c];
        acc = fmaxf(acc, 0.f) * wv[64 + tid];
#pragma unroll
        for (int off = 32; off; off >>= 1) acc += __shfl_down(acc, off);
        if (tid == 0) gcs = acc + bv[0];
    }
    __syncthreads();

    floatx4 acc[4];
#pragma unroll
    for (int ct = 0; ct < 4; ++ct) acc[ct] = (floatx4){0.f, 0.f, 0.f, 0.f};
#pragma unroll
    for (int ks = 0; ks < 2; ++ks) {
        short8 a = *(const short8*)&xs[16 * w + m15][ks * 32 + kq * 8];
#pragma unroll
        for (int ct = 0; ct < 4; ++ct) {
            short8 bfr = *(const short8*)&wns[ct * 16 + m15][ks * 32 + kq * 8];
            acc[ct] = __builtin_amdgcn_mfma_f32_16x16x32_bf16(a, bfr, acc[ct], 0, 0, 0);
        }
    }
    float bnv[4], wvv[4];
#pragma unroll
    for (int ct = 0; ct < 4; ++ct) {
        bnv[ct] = bn[ct * 16 + m15];
        wvv[ct] = wv[ct * 16 + m15];
    }
    float gc = gcs;
#pragma unroll
    for (int r = 0; r < 4; ++r) {
        float rp = 0.f;
#pragma unroll
        for (int ct = 0; ct < 4; ++ct)
            rp += fmaxf(acc[ct][r] + bnv[ct], 0.f) * wvv[ct];
#pragma unroll
        for (int off = 1; off < 16; off <<= 1) rp += __shfl_xor(rp, off);
        if (m15 == 0)
            outp[(size_t)b * NN + n0 + 16 * w + kq * 4 + r] = rp + gc;
    }
}

extern "C" void kernel_launch(void* const* d_in, const int* in_sizes, int n_in,
                              void* d_out, int out_size, void* d_ws, size_t ws_size,
                              hipStream_t stream) {
    const float* x0  = (const float*)d_in[0];
    const int*   adj = (const int*)  d_in[1];
    const float* w1  = (const float*)d_in[2];
    const float* as1 = (const float*)d_in[3];
    const float* ad1 = (const float*)d_in[4];
    const float* b1  = (const float*)d_in[5];
    const float* w2  = (const float*)d_in[6];
    const float* as2 = (const float*)d_in[7];
    const float* ad2 = (const float*)d_in[8];
    const float* b2  = (const float*)d_in[9];
    const float* w3  = (const float*)d_in[10];
    const float* as3 = (const float*)d_in[11];
    const float* ad3 = (const float*)d_in[12];
    const float* b3  = (const float*)d_in[13];
    const float* wn  = (const float*)d_in[14];
    const float* bn  = (const float*)d_in[15];
    const float* wg  = (const float*)d_in[16];
    const float* bg  = (const float*)d_in[17];
    const float* wv  = (const float*)d_in[18];
    const float* bv  = (const float*)d_in[19];
    float* outp = (float*)d_out;

    char* wsb = (char*)d_ws;
    uint64_t* amask = (uint64_t*)(wsb);                      // 1 MB
    ushort* hbT  = (ushort*)(wsb + (1u  << 20));             // 4 MB
    ushort* xbA  = (ushort*)(wsb + (5u  << 20));             // 4 MB
    ushort* xbB  = (ushort*)(wsb + (9u  << 20));             // 4 MB
    ushort* x0b  = (ushort*)(wsb + (13u << 20));             // 1 MB
    char* tail   = wsb + (14u << 20);
    float* s_buf = (float*)(tail);                           // 128 KB
    float* d_buf = (float*)(tail + (1u << 17));              // 128 KB
    ushort* wb1  = (ushort*)(tail + (2u << 17));             // 32 KB
    ushort* wb2  = (ushort*)(tail + (2u << 17) + (1u << 15));// 128 KB
    ushort* wb3  = (ushort*)(tail + (2u << 17) + (5u << 15));// 32 KB
    ushort* wnb  = (ushort*)(tail + (2u << 17) + (6u << 15));// 8 KB
    float* gsum  = (float*) (tail + (2u << 17) + (6u << 15) + (1u << 13));

    prep_all<<<2661, 256, 0, stream>>>(adj, amask, x0, w1, w2, w3, wn,
                                       x0b, wb1, wb2, wb3, wnb, gsum);

    // layer 1 (K=64, H=4)
    gemm_mfma<64><<<dim3(128, 4), 256, 0, stream>>>(x0b, wb1, hbT, as1, ad1, s_buf, d_buf, 4);
    gat_agg_mfma<<<dim3(32, 4, 8), 256, 0, stream>>>(hbT, amask, s_buf, d_buf, b1, xbA, gsum, 4, 0);

    // layer 2 (K=256, H=4)
    gemm_mfma<256><<<dim3(128, 4), 256, 0, stream>>>(xbA, wb2, hbT, as2, ad2, s_buf, d_buf, 4);
    gat_agg_mfma<<<dim3(32, 4, 8), 256, 0, stream>>>(hbT, amask, s_buf, d_buf, b2, xbB, gsum, 4, 0);

    // layer 3 (K=256, H=1) + fused column-sum
    gemm_mfma<256><<<dim3(128, 1), 256, 0, stream>>>(xbB, wb3, hbT, as3, ad3, s_buf, d_buf, 1);
    gat_agg_mfma<<<dim3(32, 1, 8), 256, 0, stream>>>(hbT, amask, s_buf, d_buf, b3, xbA, gsum, 1, 1);

    // fused readout
    readout_fused<<<dim3(16, 8), 256, 0, stream>>>(xbA, wnb, bn, wg, bg, wv, bv, gsum, outp);
}

// Round 5
// 183.258 us; speedup vs baseline: 3.0778x; 1.1374x over previous
//
#include <hip/hip_runtime.h>
#include <stdint.h>

#define NB 8
#define NN 1024
#define LOG2E 1.44269504088896f

typedef short short8 __attribute__((ext_vector_type(8)));
typedef float floatx4 __attribute__((ext_vector_type(4)));

static __device__ __forceinline__ short f2bf(float x) {   // round-nearest-even
    union { float f; uint32_t u; } v; v.f = x;
    uint32_t r = (v.u + 0x7fffu + ((v.u >> 16) & 1u)) >> 16;
    return (short)r;
}

// ---------------- prep: adjacency bitmask + fp32->bf16 cvt + gsum zero ------
__global__ __launch_bounds__(256) void prep_all(const int* __restrict__ adj,
        uint64_t* __restrict__ am,
        const float* __restrict__ x0, const float* __restrict__ w1,
        const float* __restrict__ w2, const float* __restrict__ w3,
        const float* __restrict__ wn,
        ushort* __restrict__ x0b, ushort* __restrict__ wb1,
        ushort* __restrict__ wb2, ushort* __restrict__ wb3,
        ushort* __restrict__ wnb, float* __restrict__ gsum) {
    if (blockIdx.x < 2048) {
        int wave = blockIdx.x * 4 + (threadIdx.x >> 6);
        int lane = threadIdx.x & 63;
        int b = wave >> 10;
        int i = wave & 1023;
        const int* row = adj + ((size_t)b * NN + i) * NN;
        uint64_t* outp = am + ((size_t)b * NN + i) * 16;
        for (int it = 0; it < 16; ++it) {
            int j = it * 64 + lane;
            int v = (row[j] > 0) || (j == i);
            uint64_t m = __ballot(v);
            if (lane == 0) outp[it] = m;
        }
        return;
    }
    int idx = (blockIdx.x - 2048) * 256 + threadIdx.x;
    const float* src; ushort* dst; int li;
    if (idx < 131072)      { src = x0; dst = x0b; li = idx; }
    else if (idx < 135168) { src = w1; dst = wb1; li = idx - 131072; }
    else if (idx < 151552) { src = w2; dst = wb2; li = idx - 135168; }
    else if (idx < 155648) { src = w3; dst = wb3; li = idx - 151552; }
    else if (idx < 156672) { src = wn; dst = wnb; li = idx - 155648; }
    else if (idx < 156800) {
        ((float4*)gsum)[idx - 156672] = make_float4(0.f, 0.f, 0.f, 0.f);
        return;
    } else return;
    float4 v = ((const float4*)src)[li];
    ushort4 o;
    o.x = (ushort)f2bf(v.x); o.y = (ushort)f2bf(v.y);
    o.z = (ushort)f2bf(v.z); o.w = (ushort)f2bf(v.w);
    ((ushort4*)dst)[li] = o;
}

// ---------------- MFMA GEMM: H = X @ W^T, fused s/d epilogue, LDS-transposed
template<int K>
__global__ __launch_bounds__(256, 4) void gemm_mfma(const ushort* __restrict__ X,
        const ushort* __restrict__ Wt, ushort* __restrict__ hbT,
        const float* __restrict__ asrc, const float* __restrict__ adst,
        float* __restrict__ s_t, float* __restrict__ d_t, int nheads) {
    __shared__ ushort smem[2][64][88];
    int m0 = blockIdx.x * 64, n0 = blockIdx.y * 64;
    int hd = blockIdx.y;
    int tid = threadIdx.x, w = tid >> 6, L = tid & 63;
    int m15 = L & 15, kq = L >> 4;
    floatx4 acc[4];
#pragma unroll
    for (int ct = 0; ct < 4; ++ct) acc[ct] = (floatx4){0.f, 0.f, 0.f, 0.f};

    for (int k0 = 0; k0 < K; k0 += 64) {
#pragma unroll
        for (int it = 0; it < 2; ++it) {
            int idx = tid + it * 256;
            int r = idx >> 3, sg = idx & 7;
            *(uint4*)&smem[0][r][sg * 8] = *(const uint4*)&X[(size_t)(m0 + r) * K + k0 + sg * 8];
            *(uint4*)&smem[1][r][sg * 8] = *(const uint4*)&Wt[(size_t)(n0 + r) * K + k0 + sg * 8];
        }
        __syncthreads();
#pragma unroll
        for (int ks = 0; ks < 2; ++ks) {
            short8 a = *(const short8*)&smem[0][16 * w + m15][ks * 32 + kq * 8];
#pragma unroll
            for (int ct = 0; ct < 4; ++ct) {
                short8 bfr = *(const short8*)&smem[1][ct * 16 + m15][ks * 32 + kq * 8];
                acc[ct] = __builtin_amdgcn_mfma_f32_16x16x32_bf16(a, bfr, acc[ct], 0, 0, 0);
            }
        }
        __syncthreads();
    }

    float asv[4], adv[4];
#pragma unroll
    for (int ct = 0; ct < 4; ++ct) {
        asv[ct] = asrc[hd * 64 + ct * 16 + m15];
        adv[ct] = adst[hd * 64 + ct * 16 + m15];
    }
#pragma unroll
    for (int r = 0; r < 4; ++r) {
        float sp = acc[0][r] * asv[0] + acc[1][r] * asv[1] + acc[2][r] * asv[2] + acc[3][r] * asv[3];
        float dp = acc[0][r] * adv[0] + acc[1][r] * adv[1] + acc[2][r] * adv[2] + acc[3][r] * adv[3];
#pragma unroll
        for (int off = 1; off < 16; off <<= 1) {
            sp += __shfl_xor(sp, off);
            dp += __shfl_xor(dp, off);
        }
        if (m15 == 0) {
            int mg = m0 + 16 * w + kq * 4 + r;
            int bb = mg >> 10, node = mg & 1023;
            s_t[((size_t)(bb * nheads + hd)) * NN + node] = sp;
            d_t[((size_t)(bb * nheads + hd)) * NN + node] = dp;
        }
    }

    ushort* tb = (ushort*)smem;          // stride 80
#pragma unroll
    for (int ct = 0; ct < 4; ++ct)
#pragma unroll
        for (int r = 0; r < 4; ++r)
            tb[(ct * 16 + m15) * 80 + 16 * w + kq * 4 + r] = (ushort)f2bf(acc[ct][r]);
    __syncthreads();
    int bb = m0 >> 10, node0 = m0 & 1023;
    size_t base = ((size_t)(bb * nheads + hd) * 64) * NN + node0;
    int c = tid >> 2, s2 = (tid & 3) * 2;
#pragma unroll
    for (int e = 0; e < 2; ++e) {
        int sg = s2 + e;
        *(uint4*)&hbT[base + (size_t)c * NN + sg * 8] = *(const uint4*)&tb[c * 80 + sg * 8];
    }
}

// ---------------- MFMA masked-softmax aggregation, wave-autonomous ----------
// grid (64, nheads, 8): 16-row i-tiles. Each of the 4 waves owns a private
// 8 KB LDS buffer and a j-quarter (4 chunks of 64 j), staged via register
// prefetch + ds_write: ZERO barriers in the j-loop. XOR-swizzled 16B slots
// keep B-frag ds_read_b128 conflict-free without padding. One barrier pair
// at the end combines the 4 partial accumulators + softmax denominators.
__global__ __launch_bounds__(256, 4) void gat_agg_mfma(
        const ushort* __restrict__ hbT, const uint64_t* __restrict__ am,
        const float* __restrict__ s_t, const float* __restrict__ d_t,
        const float* __restrict__ bias, ushort* __restrict__ Xb,
        float* __restrict__ gsum, int nheads, int do_colsum) {
    __shared__ float s_lds[NN];          // 4 KB
    __shared__ float red4[4];
    __shared__ ushort buf[4][4096];      // 4 × 8 KB; f32 combine overlay at end

    int i0 = blockIdx.x * 16;
    int hd = blockIdx.y;
    int b  = blockIdx.z;
    int HC = nheads * 64;
    int tid = threadIdx.x, w = tid >> 6, L = tid & 63;
    int m15 = L & 15, kq = L >> 4;

    // stage s (one float4/thread) + global max
    const float* srow = s_t + ((size_t)b * nheads + hd) * NN;
    float4 s4 = ((const float4*)srow)[tid];
    *(float4*)&s_lds[tid * 4] = s4;
    float lm = fmaxf(fmaxf(s4.x, s4.y), fmaxf(s4.z, s4.w));
#pragma unroll
    for (int off = 32; off; off >>= 1) lm = fmaxf(lm, __shfl_xor(lm, off));
    if (L == 0) red4[w] = lm;

    // per-lane adjacency words (row i0+m15, chunks w*4..w*4+3) + d_i
    const uint64_t* amrow = am + ((size_t)b * NN + i0 + m15) * 16 + w * 4;
    uint64_t aw[4];
    *(uint4*)&aw[0] = *(const uint4*)&amrow[0];
    *(uint4*)&aw[2] = *(const uint4*)&amrow[2];
    float d_i = d_t[((size_t)b * nheads + hd) * NN + i0 + m15];
    __syncthreads();

    float smax = fmaxf(fmaxf(red4[0], red4[1]), fmaxf(red4[2], red4[3]));
    float t0 = smax + d_i;
    float m_up = fmaxf(t0, 0.2f * t0);   // exp-safe upper bound (leaky monotone)
    float m2n = -m_up * LOG2E;

    floatx4 acc[4];
#pragma unroll
    for (int ct = 0; ct < 4; ++ct) acc[ct] = (floatx4){0.f, 0.f, 0.f, 0.f};
    float lsum = 0.f;

    const ushort* hbase = hbT + ((size_t)(b * nheads + hd) * 64) * NN;
    int r8 = L >> 3, sl = L & 7;
    int wofs = r8 * 64 + ((sl ^ r8) * 8);            // swizzled LDS write slot
    ushort* mybuf = buf[w];
    const ushort* gsrc = hbase + (size_t)r8 * NN + (w * 4) * 64 + sl * 8;

    uint4 pre[8];
#pragma unroll
    for (int e = 0; e < 8; ++e) pre[e] = *(const uint4*)(gsrc + (size_t)e * 8 * NN);

#pragma unroll
    for (int t = 0; t < 4; ++t) {
        int jc = w * 4 + t;
#pragma unroll
        for (int e = 0; e < 8; ++e) *(uint4*)&mybuf[wofs + e * 512] = pre[e];
        if (t < 3) {
#pragma unroll
            for (int e = 0; e < 8; ++e)
                pre[e] = *(const uint4*)(gsrc + (size_t)e * 8 * NN + (t + 1) * 64);
        }
        uint64_t word = aw[t];
#pragma unroll
        for (int ks = 0; ks < 2; ++ks) {
            int jb = jc * 64 + ks * 32 + kq * 8;
            float sv[8];
            *(float4*)&sv[0] = *(const float4*)&s_lds[jb];
            *(float4*)&sv[4] = *(const float4*)&s_lds[jb + 4];
            unsigned byte = (unsigned)((word >> (ks * 32 + kq * 8)) & 0xffull);
            unsigned ue[8];
#pragma unroll
            for (int u = 0; u < 8; ++u) {
                float sc = sv[u] + d_i;
                float lk = fmaxf(sc, 0.2f * sc);
#if __has_builtin(__builtin_amdgcn_exp2f)
                float arg = __builtin_fmaf(lk, LOG2E, m2n);
                arg = ((byte >> u) & 1u) ? arg : -1e30f;
                float e = __builtin_amdgcn_exp2f(arg);
#else
                float e = __expf(lk - m_up);
                e = ((byte >> u) & 1u) ? e : 0.f;
#endif
                lsum += e;
                ue[u] = __float_as_uint(e);
            }
            unsigned pk[4];
#pragma unroll
            for (int k2 = 0; k2 < 4; ++k2)
#if __has_builtin(__builtin_amdgcn_perm)
                pk[k2] = __builtin_amdgcn_perm(ue[2 * k2 + 1], ue[2 * k2], 0x07060302u);
#else
                pk[k2] = (ue[2 * k2] >> 16) | (ue[2 * k2 + 1] & 0xffff0000u);
#endif
            short8 afrag;
            *(uint4*)&afrag = *(uint4*)&pk[0];
            int pslot = (ks * 4 + kq) ^ (m15 & 7);
#pragma unroll
            for (int ct = 0; ct < 4; ++ct) {
                short8 bfr = *(const short8*)&mybuf[(ct * 16 + m15) * 64 + pslot * 8];
                acc[ct] = __builtin_amdgcn_mfma_f32_16x16x32_bf16(afrag, bfr, acc[ct], 0, 0, 0);
            }
        }
    }

    // partial denom for row m15 over this wave's j-quarter
    lsum += __shfl_xor(lsum, 16);
    lsum += __shfl_xor(lsum, 32);

    // publish partials into own buffer (f32 overlay [16][68] + denom row)
    float* fb = (float*)&buf[w][0];
#pragma unroll
    for (int ct = 0; ct < 4; ++ct)
#pragma unroll
        for (int r = 0; r < 4; ++r)
            fb[(kq * 4 + r) * 68 + ct * 16 + m15] = acc[ct][r];
    if (kq == 0) fb[16 * 68 + m15] = lsum;
    __syncthreads();

    // combine: thread -> (row rr, cols c0..c0+3)
    int rr = tid >> 4, c0 = (tid & 15) * 4;
    float s0 = 0.f, s1 = 0.f, s2 = 0.f, s3 = 0.f, ltot = 0.f;
#pragma unroll
    for (int w2 = 0; w2 < 4; ++w2) {
        const float* f2 = (const float*)&buf[w2][0];
        float4 a4 = *(const float4*)&f2[rr * 68 + c0];
        s0 += a4.x; s1 += a4.y; s2 += a4.z; s3 += a4.w;
        ltot += f2[16 * 68 + rr];
    }
    float li = 1.f / ltot;
    float4 bv = *(const float4*)&bias[hd * 64 + c0];
    float v0 = fmaxf(s0 * li + bv.x, 0.f);
    float v1 = fmaxf(s1 * li + bv.y, 0.f);
    float v2 = fmaxf(s2 * li + bv.z, 0.f);
    float v3 = fmaxf(s3 * li + bv.w, 0.f);
    ushort4 o;
    o.x = (ushort)f2bf(v0); o.y = (ushort)f2bf(v1);
    o.z = (ushort)f2bf(v2); o.w = (ushort)f2bf(v3);
    *(ushort4*)&Xb[((size_t)(b * NN + i0 + rr)) * HC + hd * 64 + c0] = o;

    if (do_colsum) {
        __syncthreads();
        float* cb = (float*)&buf[0][0];
        *(float4*)&cb[rr * 68 + c0] = make_float4(v0, v1, v2, v3);
        __syncthreads();
        if (tid < 64) {
            float s = 0.f;
#pragma unroll
            for (int r2 = 0; r2 < 16; ++r2) s += cb[r2 * 68 + tid];
            atomicAdd(&gsum[b * 64 + tid], s);
        }
    }
}

// ---------------- fused readout: gc + relu(X@wn.T+bn)·wv + gc ----------------
__global__ __launch_bounds__(256) void readout_fused(
        const ushort* __restrict__ xb, const ushort* __restrict__ wnb,
        const float* __restrict__ bn, const float* __restrict__ wg,
        const float* __restrict__ bg, const float* __restrict__ wv,
        const float* __restrict__ bv, const float* __restrict__ gsum,
        float* __restrict__ outp) {
    __shared__ ushort xs[64][88];
    __shared__ ushort wns[64][88];
    __shared__ float gcs;
    int b = blockIdx.y, n0 = blockIdx.x * 64;
    int tid = threadIdx.x, w = tid >> 6, L = tid & 63;
    int m15 = L & 15, kq = L >> 4;
#pragma unroll
    for (int it = 0; it < 2; ++it) {
        int idx = tid + it * 256;
        int r = idx >> 3, sg = idx & 7;
        *(uint4*)&xs[r][sg * 8]  = *(const uint4*)&xb[(size_t)(b * NN + n0 + r) * 64 + sg * 8];
        *(uint4*)&wns[r][sg * 8] = *(const uint4*)&wnb[r * 64 + sg * 8];
    }
    if (tid < 64) {
        float acc = bg[tid];
#pragma unroll 8
        for (int c = 0; c < 64; ++c) acc += gsum[b * 64 + c] * wg[tid * 64 + c];
        acc = fmaxf(acc, 0.f) * wv[64 + tid];
#pragma unroll
        for (int off = 32; off; off >>= 1) acc += __shfl_down(acc, off);
        if (tid == 0) gcs = acc + bv[0];
    }
    __syncthreads();

    floatx4 acc[4];
#pragma unroll
    for (int ct = 0; ct < 4; ++ct) acc[ct] = (floatx4){0.f, 0.f, 0.f, 0.f};
#pragma unroll
    for (int ks = 0; ks < 2; ++ks) {
        short8 a = *(const short8*)&xs[16 * w + m15][ks * 32 + kq * 8];
#pragma unroll
        for (int ct = 0; ct < 4; ++ct) {
            short8 bfr = *(const short8*)&wns[ct * 16 + m15][ks * 32 + kq * 8];
            acc[ct] = __builtin_amdgcn_mfma_f32_16x16x32_bf16(a, bfr, acc[ct], 0, 0, 0);
        }
    }
    float bnv[4], wvv[4];
#pragma unroll
    for (int ct = 0; ct < 4; ++ct) {
        bnv[ct] = bn[ct * 16 + m15];
        wvv[ct] = wv[ct * 16 + m15];
    }
    float gc = gcs;
#pragma unroll
    for (int r = 0; r < 4; ++r) {
        float rp = 0.f;
#pragma unroll
        for (int ct = 0; ct < 4; ++ct)
            rp += fmaxf(acc[ct][r] + bnv[ct], 0.f) * wvv[ct];
#pragma unroll
        for (int off = 1; off < 16; off <<= 1) rp += __shfl_xor(rp, off);
        if (m15 == 0)
            outp[(size_t)b * NN + n0 + 16 * w + kq * 4 + r] = rp + gc;
    }
}

extern "C" void kernel_launch(void* const* d_in, const int* in_sizes, int n_in,
                              void* d_out, int out_size, void* d_ws, size_t ws_size,
                              hipStream_t stream) {
    const float* x0  = (const float*)d_in[0];
    const int*   adj = (const int*)  d_in[1];
    const float* w1  = (const float*)d_in[2];
    const float* as1 = (const float*)d_in[3];
    const float* ad1 = (const float*)d_in[4];
    const float* b1  = (const float*)d_in[5];
    const float* w2  = (const float*)d_in[6];
    const float* as2 = (const float*)d_in[7];
    const float* ad2 = (const float*)d_in[8];
    const float* b2  = (const float*)d_in[9];
    const float* w3  = (const float*)d_in[10];
    const float* as3 = (const float*)d_in[11];
    const float* ad3 = (const float*)d_in[12];
    const float* b3  = (const float*)d_in[13];
    const float* wn  = (const float*)d_in[14];
    const float* bn  = (const float*)d_in[15];
    const float* wg  = (const float*)d_in[16];
    const float* bg  = (const float*)d_in[17];
    const float* wv  = (const float*)d_in[18];
    const float* bv  = (const float*)d_in[19];
    float* outp = (float*)d_out;

    char* wsb = (char*)d_ws;
    uint64_t* amask = (uint64_t*)(wsb);                      // 1 MB
    ushort* hbT  = (ushort*)(wsb + (1u  << 20));             // 4 MB
    ushort* xbA  = (ushort*)(wsb + (5u  << 20));             // 4 MB
    ushort* xbB  = (ushort*)(wsb + (9u  << 20));             // 4 MB
    ushort* x0b  = (ushort*)(wsb + (13u << 20));             // 1 MB
    char* tail   = wsb + (14u << 20);
    float* s_buf = (float*)(tail);                           // 128 KB
    float* d_buf = (float*)(tail + (1u << 17));              // 128 KB
    ushort* wb1  = (ushort*)(tail + (2u << 17));             // 32 KB
    ushort* wb2  = (ushort*)(tail + (2u << 17) + (1u << 15));// 128 KB
    ushort* wb3  = (ushort*)(tail + (2u << 17) + (5u << 15));// 32 KB
    ushort* wnb  = (ushort*)(tail + (2u << 17) + (6u << 15));// 8 KB
    float* gsum  = (float*) (tail + (2u << 17) + (6u << 15) + (1u << 13));

    prep_all<<<2661, 256, 0, stream>>>(adj, amask, x0, w1, w2, w3, wn,
                                       x0b, wb1, wb2, wb3, wnb, gsum);

    // layer 1 (K=64, H=4)
    gemm_mfma<64><<<dim3(128, 4), 256, 0, stream>>>(x0b, wb1, hbT, as1, ad1, s_buf, d_buf, 4);
    gat_agg_mfma<<<dim3(64, 4, 8), 256, 0, stream>>>(hbT, amask, s_buf, d_buf, b1, xbA, gsum, 4, 0);

    // layer 2 (K=256, H=4)
    gemm_mfma<256><<<dim3(128, 4), 256, 0, stream>>>(xbA, wb2, hbT, as2, ad2, s_buf, d_buf, 4);
    gat_agg_mfma<<<dim3(64, 4, 8), 256, 0, stream>>>(hbT, amask, s_buf, d_buf, b2, xbB, gsum, 4, 0);

    // layer 3 (K=256, H=1) + fused column-sum
    gemm_mfma<256><<<dim3(128, 1), 256, 0, stream>>>(xbB, wb3, hbT, as3, ad3, s_buf, d_buf, 1);
    gat_agg_mfma<<<dim3(64, 1, 8), 256, 0, stream>>>(hbT, amask, s_buf, d_buf, b3, xbA, gsum, 1, 1);

    // fused readout
    readout_fused<<<dim3(16, 8), 256, 0, stream>>>(xbA, wnb, bn, wg, bg, wv, bv, gsum, outp);
}